// Round 3
// baseline (2889.974 us; speedup 1.0000x reference)
//
#include <hip/hip_runtime.h>
#include <cstddef>

#define Bn 32
#define Sn 2048
#define Hn 256
#define Ln 2

typedef float f32x2 __attribute__((ext_vector_type(2)));

__device__ __forceinline__ float tanh_fast(float x) {
  // tanh(x) = 1 - 2/(exp(2x)+1); saturates correctly at +/-inf
  float e = __expf(2.0f * x);
  return 1.0f - 2.0f / (e + 1.0f);
}

// ---------------------------------------------------------------------------
// Projection GEMM: C[M,N] = A[M,K] * W[N,K]^T + bias[N]   (unchanged)
// ---------------------------------------------------------------------------
__global__ __launch_bounds__(256) void proj_gemm(
    const float* __restrict__ A,
    const float* __restrict__ W,
    const float* __restrict__ bias,
    float* __restrict__ C)
{
  __shared__ float As[64][68];
  __shared__ float Bs[64][68];
  const int tid = threadIdx.x;
  const int tx = tid & 15;   // N direction
  const int ty = tid >> 4;   // M direction
  const size_t m0 = (size_t)blockIdx.y * 64;
  const int n0 = blockIdx.x * 64;

  float acc[4][4];
#pragma unroll
  for (int i = 0; i < 4; ++i)
#pragma unroll
    for (int j = 0; j < 4; ++j) acc[i][j] = 0.0f;

  for (int kc = 0; kc < Hn; kc += 64) {
#pragma unroll
    for (int r = 0; r < 4; ++r) {
      int idx = tid + 256 * r;
      int mm = idx >> 4;
      int kk = (idx & 15) << 2;
      float4 av = *(const float4*)&A[(m0 + (size_t)mm) * Hn + kc + kk];
      As[kk + 0][mm] = av.x; As[kk + 1][mm] = av.y;
      As[kk + 2][mm] = av.z; As[kk + 3][mm] = av.w;
      float4 wv = *(const float4*)&W[(size_t)(n0 + mm) * Hn + kc + kk];
      Bs[kk + 0][mm] = wv.x; Bs[kk + 1][mm] = wv.y;
      Bs[kk + 2][mm] = wv.z; Bs[kk + 3][mm] = wv.w;
    }
    __syncthreads();
#pragma unroll
    for (int k = 0; k < 64; ++k) {
      float4 a = *(const float4*)&As[k][ty << 2];
      float4 b = *(const float4*)&Bs[k][tx << 2];
      float av4[4] = {a.x, a.y, a.z, a.w};
      float bv4[4] = {b.x, b.y, b.z, b.w};
#pragma unroll
      for (int i = 0; i < 4; ++i)
#pragma unroll
        for (int j = 0; j < 4; ++j)
          acc[i][j] += av4[i] * bv4[j];
    }
    __syncthreads();
  }

  float4 bv = *(const float4*)&bias[n0 + (tx << 2)];
  float badd[4] = {bv.x, bv.y, bv.z, bv.w};
#pragma unroll
  for (int i = 0; i < 4; ++i) {
    float4 o;
    o.x = acc[i][0] + badd[0];
    o.y = acc[i][1] + badd[1];
    o.z = acc[i][2] + badd[2];
    o.w = acc[i][3] + badd[3];
    *(float4*)&C[(m0 + (size_t)((ty << 2) + i)) * Hn + n0 + (tx << 2)] = o;
  }
}

// ---------------------------------------------------------------------------
// Recurrence: one workgroup per batch, 512 threads (8 waves).
// Wave w owns k-chunk [32w,32w+32) AND outputs [32w,32w+32).
//   - FMA phase in v_pk_fma_f32 (inline asm): 64 packed FMAs/lane instead of
//     128 scalar -> halves the VALU issue floor (512->256 cyc/SIMD), and the
//     "v" constraints force Wreg into ArchVGPRs (round 2's VGPR_Count=92
//     showed the compiler had parked W in AGPRs -> accvgpr_read tax).
//   - partials slot-major, row stride 10 words per output:
//       write addr = 10*(lane+64r) + w -> bank (10*l+w)%32, worst 4-way (~free)
//       read  addr = 10*ocol + 2*k     -> 8B-aligned ds_read_b64, 2-way (~free)
//     Each lane sums all 8 slots (4 x b64 + packed adds) -> NO shuffle.
//     Upper half-wave duplicates the reduce (broadcast reads, same issue
//     cost); only global stores are masked.
//   - single barrier/step (raw s_barrier + lgkmcnt-only wait), partials
//     double-buffered (s&1) for WAR safety.
//   - h-update wave-local: wave w reads back only its own 32 outputs.
// ---------------------------------------------------------------------------
#define PSTR 10
#define PBUF (Hn * PSTR)   // 2560 words per buffer

__global__ __launch_bounds__(512) void rnn_rec(
    const float* __restrict__ xp,   // [Bn,Sn,Hn] precomputed input projection
    const float* __restrict__ Whh,  // [Hn,Hn]
    const float* __restrict__ bhh,  // [Hn]
    const float* __restrict__ h0,   // [Bn,Hn] (layer slice)
    float* __restrict__ y,          // [Bn,Sn,Hn] layer outputs
    float* __restrict__ hfin)       // [Bn,Hn] final hidden (layer slice)
{
  const int b = blockIdx.x;
  const int t = threadIdx.x;
  const int lane = t & 63;
  const int w = t >> 6;                   // 0..7
  const int ocol = 32 * w + (lane & 31);  // output this lane reduces

  __shared__ float part[2 * PBUF];  // 2 x 10240 B
  __shared__ float hbuf[Hn];

  // Wreg[r][c2] = (Whh[lane+64r][32w+2c2], Whh[lane+64r][32w+2c2+1])
  f32x2 Wreg[4][16];
#pragma unroll
  for (int r = 0; r < 4; ++r)
#pragma unroll
    for (int q = 0; q < 8; ++q) {
      float4 v = *(const float4*)&Whh[(size_t)(lane + 64 * r) * Hn + 32 * w + 4 * q];
      Wreg[r][2 * q + 0] = f32x2{v.x, v.y};
      Wreg[r][2 * q + 1] = f32x2{v.z, v.w};
    }

  // partial-write base: part[10*(lane+64r) + w] = base + 640r (imm offsets)
  const int pw0 = PSTR * lane + w;

  const float* xp_b = xp + (size_t)b * Sn * Hn;
  float* y_b = y + (size_t)b * Sn * Hn;
  const float bias = bhh[ocol];

  // initial hv from h0 (wave-uniform broadcast loads, 8B-aligned)
  f32x2 hv[16];
#pragma unroll
  for (int c = 0; c < 16; ++c)
    hv[c] = *(const f32x2*)&h0[(size_t)b * Hn + 32 * w + 2 * c];

  float xp_cur = xp_b[ocol];

  for (int s = 0; s < Sn; ++s) {
    // prefetch next step's xp; consumed after the barrier -> latency hidden
    float xp_next = (s + 1 < Sn) ? xp_b[(size_t)(s + 1) * Hn + ocol] : 0.0f;

    // ---- FMA phase: 64 v_pk_fma_f32 per lane, all operands in ArchVGPRs
    f32x2 acc0 = {0.f, 0.f}, acc1 = {0.f, 0.f}, acc2 = {0.f, 0.f}, acc3 = {0.f, 0.f};
#pragma unroll
    for (int c = 0; c < 16; ++c) {
      asm("v_pk_fma_f32 %0, %1, %2, %0" : "+v"(acc0) : "v"(Wreg[0][c]), "v"(hv[c]));
      asm("v_pk_fma_f32 %0, %1, %2, %0" : "+v"(acc1) : "v"(Wreg[1][c]), "v"(hv[c]));
      asm("v_pk_fma_f32 %0, %1, %2, %0" : "+v"(acc2) : "v"(Wreg[2][c]), "v"(hv[c]));
      asm("v_pk_fma_f32 %0, %1, %2, %0" : "+v"(acc3) : "v"(Wreg[3][c]), "v"(hv[c]));
    }
    float* pbuf = &part[(s & 1) * PBUF];
    pbuf[pw0       ] = acc0.x + acc0.y;
    pbuf[pw0 +  640] = acc1.x + acc1.y;
    pbuf[pw0 + 1280] = acc2.x + acc2.y;
    pbuf[pw0 + 1920] = acc3.x + acc3.y;

    // partials visible to all waves; no vmcnt drain (y/xp stay in flight)
    asm volatile("s_waitcnt lgkmcnt(0)" ::: "memory");
    __builtin_amdgcn_s_barrier();
    __builtin_amdgcn_sched_barrier(0);

    // ---- reduce: every lane sums all 8 slots of its output (no shuffle)
    const f32x2* prow = (const f32x2*)&pbuf[PSTR * ocol];
    f32x2 p0 = prow[0], p1 = prow[1], p2 = prow[2], p3 = prow[3];
    f32x2 q01 = p0 + p1;          // v_pk_add_f32
    f32x2 q23 = p2 + p3;
    f32x2 qq = q01 + q23;
    float hn = tanh_fast((qq.x + qq.y) + xp_cur + bias);
    hbuf[ocol] = hn;                          // lanes l, l+32: same addr, same value
    if (lane < 32) y_b[(size_t)s * Hn + ocol] = hn;   // fire-and-forget
    xp_cur = xp_next;

    // ---- wave-local hv reload (only this wave's own 32 outputs)
    __builtin_amdgcn_wave_barrier();          // keep reads after the write
#pragma unroll
    for (int c = 0; c < 16; ++c)
      hv[c] = *(const f32x2*)&hbuf[32 * w + 2 * c];
  }

  if (lane < 32) hfin[(size_t)b * Hn + ocol] = hbuf[ocol];
}

// ---------------------------------------------------------------------------
// Phases (stream-ordered):
//  1. proj1: xp1 = x * Wih0^T + bih0          -> ws
//  2. rec1 : layer-1 recurrence, y1 -> d_out, fin0 -> d_out tail
//  3. proj2: xp2 = y1 * Wih1^T + bih1         -> ws (reuse)
//  4. rec2 : layer-2 recurrence, y2 -> d_out (final), fin1 -> d_out tail
// ws needs Bn*Sn*Hn*4 = 64 MiB.
// ---------------------------------------------------------------------------
extern "C" void kernel_launch(void* const* d_in, const int* in_sizes, int n_in,
                              void* d_out, int out_size, void* d_ws, size_t ws_size,
                              hipStream_t stream) {
  const float* x   = (const float*)d_in[0];
  const float* h0  = (const float*)d_in[1];
  const float* Wih = (const float*)d_in[2];
  const float* Whh = (const float*)d_in[3];
  const float* bih = (const float*)d_in[4];
  const float* bhh = (const float*)d_in[5];

  float* out = (float*)d_out;
  float* yout = out;                              // [Bn,Sn,Hn]
  float* fin  = out + (size_t)Bn * Sn * Hn;       // [Ln,Bn,Hn]
  float* xpws = (float*)d_ws;                     // [Bn,Sn,Hn] scratch

  dim3 pgrid(Hn / 64, (Bn * Sn) / 64);

  // layer 1
  proj_gemm<<<pgrid, 256, 0, stream>>>(x, Wih, bih, xpws);
  rnn_rec<<<Bn, 512, 0, stream>>>(xpws, Whh, bhh, h0, yout, fin);

  // layer 2 (input = y1 currently residing in d_out)
  proj_gemm<<<pgrid, 256, 0, stream>>>(yout, Wih + Hn * Hn, bih + Hn, xpws);
  rnn_rec<<<Bn, 512, 0, stream>>>(xpws, Whh + Hn * Hn, bhh + Hn,
                                  h0 + Bn * Hn, yout, fin + Bn * Hn);
}